// Round 12
// baseline (513.421 us; speedup 1.0000x reference)
//
#include <hip/hip_runtime.h>
#include <hip/hip_bf16.h>

#define B_SZ   2048
#define F_IN   1024
#define R_EMB  1024
#define F_OUT  1024
#define F_MID  2048
#define NNZ_E  65536
#define NNZ_W  131072
#define NNZ_B  512
#define NBLK   512

typedef __bf16 bf16x8 __attribute__((ext_vector_type(8)));
typedef float  f32x4  __attribute__((ext_vector_type(4)));

__device__ inline void gload16(const void* g, void* l) {
    __builtin_amdgcn_global_load_lds(
        (const __attribute__((address_space(1))) void*)g,
        (__attribute__((address_space(3))) void*)l, 16, 0, 0);
}

__device__ inline ushort f2bf(float v) {
    __hip_bfloat16 h = __float2bfloat16(v);
    return *reinterpret_cast<ushort*>(&h);
}

// Grid barrier for a 512-block grid (2 blocks/CU = half device capacity;
// launch_bounds(256,2) + 32 KB LDS make co-residency structural; R10 measured
// 24.9% occupancy = exactly 2 blocks/CU, so arrivals always complete).
// R10 lesson #1: barrier state MUST NOT overlap any live buffer (it sat inside
// Wbf's last page and was clobbered by cvt).  Now at +64 MB, nothing within 38 MB.
// R10 lesson #2: bounded spin, but tight: 1<<16 sleep-iters ~ 3 ms worst case
// (real wait < 50 us), so a logic failure costs ms per call, not minutes.
__device__ __forceinline__ void gridbar(int* cnt, int* gen, int next) {
    __threadfence();
    __syncthreads();
    if (threadIdx.x == 0) {
        int prev = __hip_atomic_fetch_add(cnt, 1, __ATOMIC_ACQ_REL,
                                          __HIP_MEMORY_SCOPE_AGENT);
        if (prev == NBLK - 1) {
            __hip_atomic_store(cnt, 0, __ATOMIC_RELAXED, __HIP_MEMORY_SCOPE_AGENT);
            __hip_atomic_store(gen, next, __ATOMIC_RELEASE, __HIP_MEMORY_SCOPE_AGENT);
        } else {
            int iters = 0;
            while (__hip_atomic_load(gen, __ATOMIC_ACQUIRE,
                                     __HIP_MEMORY_SCOPE_AGENT) < next &&
                   ++iters < (1 << 16))
                __builtin_amdgcn_s_sleep(2);
        }
    }
    __syncthreads();
    __threadfence();
}

// R6 64x64x64 GEMM core (2-phase dbuf, XOR chunk-swizzle, 4 waves of 32x32
// wave tiles, 16x16x32 MFMA).
//   mode 0: h = relu(A @ Bm^T)      -> bf16 hOut (x2 right half)
//   mode 1: out = A @ Bm^T + bias   -> f32
//   mode 2: out += A @ Bm^T         -> f32 RMW
__device__ __forceinline__ void gemm64(
    ushort (*lds)[2][64 * 64],
    int mode, int m0, int n0,
    const ushort* __restrict__ A, const ushort* __restrict__ Bm, int ldb,
    const float* __restrict__ biasd, float* __restrict__ out,
    ushort* __restrict__ hOut)
{
    constexpr int BK = 64, NT = 16;
    const int tid = threadIdx.x;
    const int w = tid >> 6, l = tid & 63;
    const int wr = w >> 1, wc = w & 1;
    const int la = l & 15;
    const int srow = w * 8 + (l >> 3);
    const int ldst = w * 512 + l * 8;

    f32x4 acc[2][2] = {};

    #define STAGE(buf, k0)                                                      \
        _Pragma("unroll")                                                       \
        for (int i = 0; i < 2; ++i) {                                           \
            int row = i * 32 + srow;                                            \
            int scol = (k0) + ((((l & 7) ^ (row & 7))) << 3);                   \
            gload16(A  + (size_t)(m0 + row) * F_MID + scol,                     \
                    &lds[buf][0][i * 2048 + ldst]);                             \
            gload16(Bm + (size_t)(n0 + row) * ldb + scol,                       \
                    &lds[buf][1][i * 2048 + ldst]);                             \
        }

    STAGE(0, 0);
    __syncthreads();

    for (int t = 0; t < NT; ++t) {
        const int cur = t & 1;
        if (t + 1 < NT) STAGE(cur ^ 1, (t + 1) * BK);

        const ushort* sA = &lds[cur][0][0];
        const ushort* sB = &lds[cur][1][0];
        #pragma unroll
        for (int ks = 0; ks < 2; ++ks) {
            const int k8 = ks * 4 + (l >> 4);
            bf16x8 af[2], bg[2];
            #pragma unroll
            for (int m = 0; m < 2; ++m) {
                int row = wr * 32 + m * 16 + la;
                af[m] = *(const bf16x8*)(sA + row * BK + ((k8 ^ (row & 7)) << 3));
            }
            #pragma unroll
            for (int n = 0; n < 2; ++n) {
                int row = wc * 32 + n * 16 + la;
                bg[n] = *(const bf16x8*)(sB + row * BK + ((k8 ^ (row & 7)) << 3));
            }
            #pragma unroll
            for (int m = 0; m < 2; ++m)
                #pragma unroll
                for (int n = 0; n < 2; ++n)
                    acc[m][n] = __builtin_amdgcn_mfma_f32_16x16x32_bf16(
                        af[m], bg[n], acc[m][n], 0, 0, 0);
        }
        __syncthreads();
    }
    #undef STAGE

    // C/D layout (verified m89/m91): col = lane&15, row = (lane>>4)*4 + reg.
    const int lr = (l >> 4) * 4;
    #pragma unroll
    for (int m = 0; m < 2; ++m) {
        #pragma unroll
        for (int n = 0; n < 2; ++n) {
            const int col = n0 + wc * 32 + n * 16 + la;
            if (mode == 0) {
                #pragma unroll
                for (int j = 0; j < 4; ++j) {
                    int row = m0 + wr * 32 + m * 16 + lr + j;
                    hOut[(size_t)row * F_MID + col] = f2bf(fmaxf(acc[m][n][j], 0.f));
                }
            } else if (mode == 1) {
                const float bv = biasd[col];
                #pragma unroll
                for (int j = 0; j < 4; ++j) {
                    int row = m0 + wr * 32 + m * 16 + lr + j;
                    out[(size_t)row * F_OUT + col] = acc[m][n][j] + bv;
                }
            } else {
                #pragma unroll
                for (int j = 0; j < 4; ++j) {
                    int row = m0 + wr * 32 + m * 16 + lr + j;
                    out[(size_t)row * F_OUT + col] += acc[m][n][j];
                }
            }
        }
    }
}

// Single persistent kernel: zero -> scatter -> cvt -> GEMM A -> GEMM B,
// separated by in-kernel grid barriers (no launch gaps, no dispatch ramps).
__global__ __launch_bounds__(256, 2)
void k_mega(const float* __restrict__ x,
            const int* __restrict__ er, const int* __restrict__ ec,
            const float* __restrict__ ev,
            const int* __restrict__ wr_, const int* __restrict__ wc_,
            const float* __restrict__ wv,
            const int* __restrict__ bi, const float* __restrict__ bv,
            float* __restrict__ out,
            ushort* __restrict__ x2,   float* __restrict__ Wf,
            float* __restrict__ Ef,    float* __restrict__ biasd,
            ushort* __restrict__ Ebf,  ushort* __restrict__ Wbf,
            int* __restrict__ bar)
{
    __shared__ ushort lds[2][2][64 * 64];   // 32 KB
    int* cnt = bar;
    int* gen = bar + 1;
    const int blk = blockIdx.x, tid = threadIdx.x;
    const int gidx = blk * 256 + tid;       // 0 .. 131071

    // ---- phase 0: zero Wf | Ef | bias (contiguous 12 MB + 4 KB = 786688 f4)
    {
        float4* zb = (float4*)Wf;
        float4 z = make_float4(0.f, 0.f, 0.f, 0.f);
        for (int i = gidx; i < 786688; i += NBLK * 256) zb[i] = z;
    }
    gridbar(cnt, gen, 1);

    // ---- phase 1: scatter-add (device-scope atomics -> XCD-coherent)
    for (int i = gidx; i < NNZ_E + NNZ_W + NNZ_B; i += NBLK * 256) {
        if (i < NNZ_E) {
            atomicAdd(&Ef[(size_t)er[i] * F_IN + ec[i]], ev[i]);
        } else if (i < NNZ_E + NNZ_W) {
            int j = i - NNZ_E;
            atomicAdd(&Wf[(size_t)wr_[j] * F_MID + wc_[j]], wv[j]);
        } else {
            int j = i - (NNZ_E + NNZ_W);
            atomicAdd(&biasd[bi[j]], bv[j]);
        }
    }
    gridbar(cnt, gen, 2);

    // ---- phase 2: f32 -> bf16 (x into x2 left half; Ef->Ebf; Wf->Wbf)
    for (int i = gidx; i < 1310720; i += NBLK * 256) {
        if (i < 524288) {
            float4 v = ((const float4*)x)[i];
            int row = i >> 8, c4 = i & 255;
            ((ushort4*)x2)[(size_t)row * (F_MID / 4) + c4] =
                make_ushort4(f2bf(v.x), f2bf(v.y), f2bf(v.z), f2bf(v.w));
        } else if (i < 786432) {
            int j = i - 524288;
            float4 v = ((const float4*)Ef)[j];
            ((ushort4*)Ebf)[j] = make_ushort4(f2bf(v.x), f2bf(v.y), f2bf(v.z), f2bf(v.w));
        } else {
            int j = i - 786432;
            float4 v = ((const float4*)Wf)[j];
            ((ushort4*)Wbf)[j] = make_ushort4(f2bf(v.x), f2bf(v.y), f2bf(v.z), f2bf(v.w));
        }
    }
    gridbar(cnt, gen, 3);

    // ---- phase 3: GEMM A  {h = relu(x @ E^T)}  then  {out = x @ W_L^T + bias}
    //      2 sequential tiles/block; all-h-first so all blocks share Ebf in L2.
    {
        int tt = blk;                               // by 0..15 -> mode 0
        gemm64(lds, 0, (tt & 31) * 64, (tt >> 5) * 64,
               x2, Ebf, F_IN, biasd, out, x2 + F_IN);
        tt = blk + 512;                             // by 16..31 -> mode 1
        gemm64(lds, 1, (tt & 31) * 64, ((tt >> 5) - 16) * 64,
               x2, Wbf, F_MID, biasd, out, x2 + F_IN);
    }
    gridbar(cnt, gen, 4);

    // ---- phase 4: GEMM B  out += h @ W_R^T   (one tile per block)
    gemm64(lds, 2, (blk & 31) * 64, (blk >> 5) * 64,
           x2 + F_IN, Wbf + F_IN, F_MID, biasd, out, x2 + F_IN);
}

extern "C" void kernel_launch(void* const* d_in, const int* in_sizes, int n_in,
                              void* d_out, int out_size, void* d_ws, size_t ws_size,
                              hipStream_t stream) {
    const float* x          = (const float*)d_in[0];
    const int*   embed_rows = (const int*)  d_in[1];
    const int*   embed_cols = (const int*)  d_in[2];
    const float* embed_vals = (const float*)d_in[3];
    const int*   w_rows     = (const int*)  d_in[4];
    const int*   w_cols     = (const int*)  d_in[5];
    const float* w_vals     = (const float*)d_in[6];
    const int*   bias_idx   = (const int*)  d_in[7];
    const float* bias_vals  = (const float*)d_in[8];
    float* out = (float*)d_out;

    // Workspace layout (live data ends at 26M+4K; barrier at 64M, far clear):
    //   [0, 8M)          x2 bf16 [2048][2048]  (left = x, right = relu h)
    //   [8M, 16M)        W_f32 [1024][2048]
    //   [16M, 20M)       E_f32 [1024][1024]
    //   [20M, 20M+4K)    bias f32 [1024]
    //   [20M+4K, 22M+4K) E_bf16 [1024][1024]
    //   [22M+4K, 26M+4K) W_bf16 [1024][2048]
    //   [64M, 64M+8)     grid-barrier {cnt, gen}   (R10 bug: this was at 26M,
    //                    INSIDE Wbf's last page -> clobbered by cvt)
    char* ws = (char*)d_ws;
    ushort* x2    = (ushort*)ws;
    float*  Wf    = (float*)(ws + (8u << 20));
    float*  Ef    = (float*)(ws + (16u << 20));
    float*  biasd = (float*)(ws + (20u << 20));
    ushort* Ebf   = (ushort*)(ws + (20u << 20) + 4096);
    ushort* Wbf   = (ushort*)(ws + (22u << 20) + 4096);
    int*    bar   = (int*)(ws + (64u << 20));

    // Re-zero barrier state every call (graph-replay deterministic).
    hipMemsetAsync(bar, 0, 8, stream);

    k_mega<<<NBLK, 256, 0, stream>>>(x,
                                     embed_rows, embed_cols, embed_vals,
                                     w_rows, w_cols, w_vals,
                                     bias_idx, bias_vals,
                                     out, x2, Wf, Ef, biasd, Ebf, Wbf, bar);
}

// Round 13
// 52.450 us; speedup vs baseline: 9.7887x; 9.7887x over previous
//
#include <hip/hip_runtime.h>
#include <hip/hip_bf16.h>

#define B_SZ   2048
#define F_IN   1024
#define R_EMB  1024
#define F_OUT  1024
#define F_MID  2048
#define NNZ_E  65536
#define NNZ_W  131072
#define NNZ_B  512

typedef __bf16 bf16x8 __attribute__((ext_vector_type(8)));
typedef float  f32x4  __attribute__((ext_vector_type(4)));

__device__ inline void gload16(const void* g, void* l) {
    __builtin_amdgcn_global_load_lds(
        (const __attribute__((address_space(1))) void*)g,
        (__attribute__((address_space(3))) void*)l, 16, 0, 0);
}

__device__ inline ushort f2bf(float v) {
    __hip_bfloat16 h = __float2bfloat16(v);
    return *reinterpret_cast<ushort*>(&h);
}

__device__ inline float bf2f(ushort u) {
    uint w = (uint)u << 16;
    float f;
    __builtin_memcpy(&f, &w, 4);
    return f;
}

// bf16 scatter-add via 32-bit CAS on the containing word.  Handles duplicate
// (r,c) entries and false sharing with the neighboring bf16.  ~6% fill ->
// expected CAS iterations ~1.  (R12 lesson: in-kernel grid barriers cost
// ~100 us each on gfx950 — fixing the DAG beats fusing it.)
__device__ inline void bf16_scatter_add(ushort* addr, float val) {
    uint* word = (uint*)((uintptr_t)addr & ~(uintptr_t)3);
    const bool hi = ((uintptr_t)addr & 2) != 0;
    uint old = __hip_atomic_load(word, __ATOMIC_RELAXED, __HIP_MEMORY_SCOPE_AGENT);
    while (true) {
        ushort cur = hi ? (ushort)(old >> 16) : (ushort)(old & 0xffffu);
        ushort nv  = f2bf(bf2f(cur) + val);
        uint neww  = hi ? ((old & 0x0000ffffu) | ((uint)nv << 16))
                        : ((old & 0xffff0000u) | (uint)nv);
        uint prev = atomicCAS(word, old, neww);
        if (prev == old) break;
        old = prev;
    }
}

__global__ void k_zero4(float4* __restrict__ p, int n) {
    int i = blockIdx.x * blockDim.x + threadIdx.x;
    if (i < n) p[i] = make_float4(0.f, 0.f, 0.f, 0.f);
}

// One launch: x f32->bf16 into x2 left half, E/W CAS-scatter directly to bf16
// dense, bias f32 scatter.  Blocks partitioned by range.
__global__ void k_prep(const float4* __restrict__ x, ushort* __restrict__ x2,
                       const int* __restrict__ er, const int* __restrict__ ec,
                       const float* __restrict__ ev,
                       const int* __restrict__ wr_, const int* __restrict__ wc_,
                       const float* __restrict__ wv,
                       const int* __restrict__ bi, const float* __restrict__ bv,
                       ushort* __restrict__ Ebf, ushort* __restrict__ Wbf,
                       float* __restrict__ biasd) {
    int b = blockIdx.x, t = threadIdx.x;
    if (b < 2048) {                          // x convert: 524288 float4
        int i = b * 256 + t;
        int row = i >> 8, c4 = i & 255;      // 256 float4 per row of 1024
        float4 v = x[i];
        ((ushort4*)x2)[(size_t)row * (F_MID / 4) + c4] =
            make_ushort4(f2bf(v.x), f2bf(v.y), f2bf(v.z), f2bf(v.w));
    } else if (b < 2048 + NNZ_E / 256) {     // E scatter
        int i = (b - 2048) * 256 + t;
        bf16_scatter_add(&Ebf[(size_t)er[i] * F_IN + ec[i]], ev[i]);
    } else if (b < 2048 + NNZ_E / 256 + NNZ_W / 256) {   // W scatter
        int i = (b - 2048 - NNZ_E / 256) * 256 + t;
        bf16_scatter_add(&Wbf[(size_t)wr_[i] * F_MID + wc_[i]], wv[i]);
    } else {                                 // bias scatter: 2 blocks
        int i = (b - 2048 - NNZ_E / 256 - NNZ_W / 256) * 256 + t;
        atomicAdd(&biasd[bi[i]], bv[i]);
    }
}

// GEMM-A' (dual-B fusion, R11-proven): one block per (m0,n0) stages its A-tile
// once and computes BOTH h = relu(x @ E^T) and out = x @ W_L^T + bias.
// 64x64x64 tiles, 2-phase dbuf, XOR chunk-swizzle, 4 waves of 32x32 wave
// tiles, 16x16x32 MFMA.  Bijective XCD chunk swizzle on blockIdx.
__global__ __launch_bounds__(256)
void k_gemmA(const ushort* __restrict__ x2,   // [2048][2048] bf16 (left half = x)
             const ushort* __restrict__ Ebf,  // [1024][1024] bf16
             const ushort* __restrict__ Wbf,  // [1024][2048] bf16
             const float* __restrict__ biasd, // [1024]
             float* __restrict__ out,         // [2048][1024] f32
             ushort* __restrict__ hOut)       // = x2 + F_IN
{
    constexpr int BK = 64, NT = 16;
    __shared__ ushort lds[2][3][64 * 64];     // [buf][A|BE|BW], 48 KB
    const int tid = threadIdx.x;
    const int w = tid >> 6, l = tid & 63;
    const int wr = w >> 1, wc = w & 1;
    const int la = l & 15;

    const int blk = blockIdx.x;               // 512 blocks
    const int sw  = (blk & 7) * 64 + (blk >> 3);   // XCD chunk swizzle
    const int m0  = (sw >> 4) * 64;
    const int n0  = (sw & 15) * 64;

    const int srow = w * 8 + (l >> 3);
    const int ldst = w * 512 + l * 8;

    f32x4 accE[2][2] = {}, accW[2][2] = {};

    #define STAGE(buf, k0)                                                      \
        _Pragma("unroll")                                                       \
        for (int i = 0; i < 2; ++i) {                                           \
            int row = i * 32 + srow;                                            \
            int scol = (k0) + ((((l & 7) ^ (row & 7))) << 3);                   \
            gload16(x2  + (size_t)(m0 + row) * F_MID + scol,                    \
                    &lds[buf][0][i * 2048 + ldst]);                             \
            gload16(Ebf + (size_t)(n0 + row) * F_IN + scol,                     \
                    &lds[buf][1][i * 2048 + ldst]);                             \
            gload16(Wbf + (size_t)(n0 + row) * F_MID + scol,                    \
                    &lds[buf][2][i * 2048 + ldst]);                             \
        }

    STAGE(0, 0);
    __syncthreads();

    for (int t = 0; t < NT; ++t) {
        const int cur = t & 1;
        if (t + 1 < NT) STAGE(cur ^ 1, (t + 1) * BK);

        const ushort* sA  = &lds[cur][0][0];
        const ushort* sBE = &lds[cur][1][0];
        const ushort* sBW = &lds[cur][2][0];
        #pragma unroll
        for (int ks = 0; ks < 2; ++ks) {
            const int k8 = ks * 4 + (l >> 4);
            bf16x8 af[2], be[2], bw[2];
            #pragma unroll
            for (int m = 0; m < 2; ++m) {
                int row = wr * 32 + m * 16 + la;
                af[m] = *(const bf16x8*)(sA + row * BK + ((k8 ^ (row & 7)) << 3));
            }
            #pragma unroll
            for (int n = 0; n < 2; ++n) {
                int row = wc * 32 + n * 16 + la;
                be[n] = *(const bf16x8*)(sBE + row * BK + ((k8 ^ (row & 7)) << 3));
                bw[n] = *(const bf16x8*)(sBW + row * BK + ((k8 ^ (row & 7)) << 3));
            }
            #pragma unroll
            for (int m = 0; m < 2; ++m)
                #pragma unroll
                for (int n = 0; n < 2; ++n) {
                    accE[m][n] = __builtin_amdgcn_mfma_f32_16x16x32_bf16(
                        af[m], be[n], accE[m][n], 0, 0, 0);
                    accW[m][n] = __builtin_amdgcn_mfma_f32_16x16x32_bf16(
                        af[m], bw[n], accW[m][n], 0, 0, 0);
                }
        }
        __syncthreads();
    }
    #undef STAGE

    // C/D layout (verified m89/m91): col = lane&15, row = (lane>>4)*4 + reg.
    const int lr = (l >> 4) * 4;
    #pragma unroll
    for (int m = 0; m < 2; ++m) {
        #pragma unroll
        for (int n = 0; n < 2; ++n) {
            const int col = n0 + wc * 32 + n * 16 + la;
            const float bv = biasd[col];
            #pragma unroll
            for (int j = 0; j < 4; ++j) {
                const int row = m0 + wr * 32 + m * 16 + lr + j;
                hOut[(size_t)row * F_MID + col] = f2bf(fmaxf(accE[m][n][j], 0.f));
                out[(size_t)row * F_OUT + col]  = accW[m][n][j] + bv;
            }
        }
    }
}

// GEMM-B: out += h @ W_R^T  (R6 mode-2 core, XCD swizzle).
__global__ __launch_bounds__(256)
void k_gemmB(const ushort* __restrict__ x2,   // h = x2 + F_IN
             const ushort* __restrict__ Wbf,
             float* __restrict__ out)
{
    constexpr int BK = 64, NT = 16;
    __shared__ ushort lds[2][2][64 * 64];
    const int tid = threadIdx.x;
    const int w = tid >> 6, l = tid & 63;
    const int wr = w >> 1, wc = w & 1;
    const int la = l & 15;

    const int blk = blockIdx.x;
    const int sw  = (blk & 7) * 64 + (blk >> 3);
    const int m0  = (sw >> 4) * 64;
    const int n0  = (sw & 15) * 64;

    const ushort* A  = x2 + F_IN;
    const ushort* Bm = Wbf + F_IN;

    const int srow = w * 8 + (l >> 3);
    const int ldst = w * 512 + l * 8;

    f32x4 acc[2][2] = {};

    #define STAGE(buf, k0)                                                      \
        _Pragma("unroll")                                                       \
        for (int i = 0; i < 2; ++i) {                                           \
            int row = i * 32 + srow;                                            \
            int scol = (k0) + ((((l & 7) ^ (row & 7))) << 3);                   \
            gload16(A  + (size_t)(m0 + row) * F_MID + scol,                     \
                    &lds[buf][0][i * 2048 + ldst]);                             \
            gload16(Bm + (size_t)(n0 + row) * F_MID + scol,                     \
                    &lds[buf][1][i * 2048 + ldst]);                             \
        }

    STAGE(0, 0);
    __syncthreads();

    for (int t = 0; t < NT; ++t) {
        const int cur = t & 1;
        if (t + 1 < NT) STAGE(cur ^ 1, (t + 1) * BK);

        const ushort* sA = &lds[cur][0][0];
        const ushort* sB = &lds[cur][1][0];
        #pragma unroll
        for (int ks = 0; ks < 2; ++ks) {
            const int k8 = ks * 4 + (l >> 4);
            bf16x8 af[2], bg[2];
            #pragma unroll
            for (int m = 0; m < 2; ++m) {
                int row = wr * 32 + m * 16 + la;
                af[m] = *(const bf16x8*)(sA + row * BK + ((k8 ^ (row & 7)) << 3));
            }
            #pragma unroll
            for (int n = 0; n < 2; ++n) {
                int row = wc * 32 + n * 16 + la;
                bg[n] = *(const bf16x8*)(sB + row * BK + ((k8 ^ (row & 7)) << 3));
            }
            #pragma unroll
            for (int m = 0; m < 2; ++m)
                #pragma unroll
                for (int n = 0; n < 2; ++n)
                    acc[m][n] = __builtin_amdgcn_mfma_f32_16x16x32_bf16(
                        af[m], bg[n], acc[m][n], 0, 0, 0);
        }
        __syncthreads();
    }
    #undef STAGE

    const int lr = (l >> 4) * 4;
    #pragma unroll
    for (int m = 0; m < 2; ++m) {
        #pragma unroll
        for (int n = 0; n < 2; ++n) {
            const int col = n0 + wc * 32 + n * 16 + la;
            #pragma unroll
            for (int j = 0; j < 4; ++j) {
                const int row = m0 + wr * 32 + m * 16 + lr + j;
                out[(size_t)row * F_OUT + col] += acc[m][n][j];
            }
        }
    }
}

extern "C" void kernel_launch(void* const* d_in, const int* in_sizes, int n_in,
                              void* d_out, int out_size, void* d_ws, size_t ws_size,
                              hipStream_t stream) {
    const float* x          = (const float*)d_in[0];
    const int*   embed_rows = (const int*)  d_in[1];
    const int*   embed_cols = (const int*)  d_in[2];
    const float* embed_vals = (const float*)d_in[3];
    const int*   w_rows     = (const int*)  d_in[4];
    const int*   w_cols     = (const int*)  d_in[5];
    const float* w_vals     = (const float*)d_in[6];
    const int*   bias_idx   = (const int*)  d_in[7];
    const float* bias_vals  = (const float*)d_in[8];
    float* out = (float*)d_out;

    // Workspace layout (~26 MB; f32 dense staging buffers eliminated):
    //   [0, 8M)          x2 bf16 [2048][2048]  (left = x, right = relu h)
    //   [20M, 20M+4K)    bias f32 [1024]
    //   [20M+4K, 22M+4K) E_bf16 [1024][1024]
    //   [22M+4K, 26M+4K) W_bf16 [1024][2048]
    //   (bias|Ebf|Wbf contiguous -> one 6MB+4KB zero pass)
    char* ws = (char*)d_ws;
    ushort* x2    = (ushort*)ws;
    float*  biasd = (float*)(ws + (20u << 20));
    ushort* Ebf   = (ushort*)(ws + (20u << 20) + 4096);
    ushort* Wbf   = (ushort*)(ws + (22u << 20) + 4096);

    // 1. zero biasd | Ebf | Wbf (contiguous 6 MB + 4 KB = 393472 float4)
    k_zero4<<<1537, 256, 0, stream>>>((float4*)biasd, 393472);

    // 2. x-cvt + direct-bf16 CAS scatter (E, W) + bias scatter (one launch)
    k_prep<<<2048 + NNZ_E / 256 + NNZ_W / 256 + NNZ_B / 256, 256, 0, stream>>>(
        (const float4*)x, x2,
        embed_rows, embed_cols, embed_vals,
        w_rows, w_cols, w_vals,
        bias_idx, bias_vals, Ebf, Wbf, biasd);

    // 3. GEMM-A': dual-B fused  {h = relu(x @ E^T)} + {out = x @ W_L^T + bias}
    k_gemmA<<<512, 256, 0, stream>>>(x2, Ebf, Wbf, biasd, out, x2 + F_IN);

    // 4. GEMM-B: out += h @ W_R^T
    k_gemmB<<<512, 256, 0, stream>>>(x2, Wbf, out);
}